// Round 1
// baseline (250.338 us; speedup 1.0000x reference)
//
#include <hip/hip_runtime.h>
#include <math.h>

#define FIELD  39
#define NPF    38      // fields participating in pairwise term (0..37)
#define NPAIRS 703     // C(38,2)
#define FEAT   100000
#define EMB    10

__global__ __launch_bounds__(256) void ffm_kernel(
    const int*   __restrict__ idxs,   // [B, 39]
    const float* __restrict__ vals,   // [B, 39]
    const float* __restrict__ emb,    // [39, 100000, 10]
    const float* __restrict__ w1,     // [100000, 1]
    float*       __restrict__ out)    // [B]
{
    const int b = blockIdx.x;
    const int t = threadIdx.x;

    __shared__ int   s_idx[FIELD];
    __shared__ float s_val[FIELD];
    if (t < FIELD) {
        s_idx[t] = idxs[b * FIELD + t];
        s_val[t] = vals[b * FIELD + t];
    }
    __syncthreads();

    float acc = 0.f;
    // first-order term: sum_f w1[idx[b,f]] * val[b,f]  (all 39 fields)
    if (t < FIELD) acc = w1[s_idx[t]] * s_val[t];

    // pairwise term: pairs (i,j), 0 <= i < j <= 37
    for (int p = t; p < NPAIRS; p += 256) {
        // decode linear pair index -> (i, j); pairs with first index i number (37 - i)
        int i = 0, rem = p;
        while (rem >= NPF - 1 - i) { rem -= NPF - 1 - i; ++i; }
        const int j = i + 1 + rem;

        // rows are 10 floats = 40 B, offsets multiples of 40 B -> 8 B aligned
        const float2* ea = (const float2*)(emb + ((size_t)i * FEAT + s_idx[j]) * EMB);
        const float2* eb = (const float2*)(emb + ((size_t)j * FEAT + s_idx[i]) * EMB);
        float s = 0.f;
        #pragma unroll
        for (int e = 0; e < 5; ++e) {
            const float2 x = ea[e];
            const float2 y = eb[e];
            s += x.x * y.x + x.y * y.y;
        }
        acc += s * s_val[i] * s_val[j];
    }

    // block reduction: wave64 shuffle, then 4 partials through LDS
    #pragma unroll
    for (int off = 32; off > 0; off >>= 1)
        acc += __shfl_down(acc, off, 64);

    __shared__ float wsum[4];
    if ((t & 63) == 0) wsum[t >> 6] = acc;
    __syncthreads();
    if (t == 0) {
        const float tot = wsum[0] + wsum[1] + wsum[2] + wsum[3];
        out[b] = 1.f / (1.f + expf(-tot));
    }
}

extern "C" void kernel_launch(void* const* d_in, const int* in_sizes, int n_in,
                              void* d_out, int out_size, void* d_ws, size_t ws_size,
                              hipStream_t stream) {
    const int*   idxs = (const int*)  d_in[0];   // [2048, 39] int32
    const float* vals = (const float*)d_in[1];   // [2048, 39] f32
    const float* emb  = (const float*)d_in[2];   // [39, 100000, 10] f32
    const float* w1   = (const float*)d_in[3];   // [100000, 1] f32
    float*       out  = (float*)d_out;           // [2048] f32

    ffm_kernel<<<out_size, 256, 0, stream>>>(idxs, vals, emb, w1, out);
}